// Round 9
// baseline (1082.517 us; speedup 1.0000x reference)
//
#include <hip/hip_runtime.h>

#define NN 50000
#define NE 800000
#define DD 64
#define NL 5
#define NG 256
#define NC 10
#define BN_EPS 1e-5f
#define NCHUNK ((NN + 255) / 256)   // 196
#define GROWS 64                     // rows per gemm block
#define GT (GROWS / 16)              // 16-row tiles per block
#define SAW 68                       // staged-A row stride (uints): 2-way conflicts only

// phased gather params
#define NPW 8                        // nodes per wave
#define PHASES 4
#define PBOUND 12500                 // src-partition width (3.2 MB QVp slice)
#define SORT_CAP 48                  // max degree sorted (Poisson(16): P(>48)~0)

typedef __attribute__((ext_vector_type(8))) short bf16x8;
typedef __attribute__((ext_vector_type(4))) float f32x4;

// Pack two floats as bf16 (RNE) into one uint: low16 = q, high16 = v.
__device__ inline unsigned int pack_bf16x2(float q, float v) {
    unsigned int uq = __float_as_uint(q);
    unsigned int uv = __float_as_uint(v);
    uq += 0x7FFFu + ((uq >> 16) & 1u);
    uv += 0x7FFFu + ((uv >> 16) & 1u);
    return (uv & 0xFFFF0000u) | (uq >> 16);
}

__device__ inline float sigmoidf_fast(float x) {
    return 1.f / (1.f + __expf(-x));
}

// Split fp32 into bf16 hi (RTZ) + bf16 lo (residual). hi+lo ~ x to ~2^-17.
__device__ inline void split_bf16(float x, short& h, short& l) {
    const unsigned u  = __float_as_uint(x);
    const unsigned hb = u & 0xFFFF0000u;
    h = (short)(hb >> 16);
    const float lo = x - __uint_as_float(hb);
    l = (short)(__float_as_uint(lo) >> 16);
}

// gate-fma for one packed bf16 q|v edge value
__device__ inline float gate_fma(float k, unsigned p, float acc) {
    const float q = __uint_as_float(p << 16);
    const float v = __uint_as_float(p & 0xFFFF0000u);
    return fmaf(sigmoidf_fast(k + q), v, acc);
}

// ---------------------------------------------------------------------------
// MFMA gemm4 (unchanged): K/Q/V/S = BN(Hin) @ W* + b*. Split-bf16, 3 MFMAs
// per 16x16x32 product, fp32 accumulate. BN of previous layer folded.
// ---------------------------------------------------------------------------
__global__ __launch_bounds__(256) void gemm4_mfma(
    const float* __restrict__ Hin,
    const float* __restrict__ Wk, const float* __restrict__ Wq,
    const float* __restrict__ Wv, const float* __restrict__ Ws,
    const float* __restrict__ bk, const float* __restrict__ bq,
    const float* __restrict__ bv, const float* __restrict__ bs,
    const float* __restrict__ prevStats,   // null for layer 0
    const float* __restrict__ prevGamma, const float* __restrict__ prevBeta,
    float* __restrict__ K, unsigned int* __restrict__ QVp,
    float* __restrict__ OUT)
{
    __shared__ unsigned int sA[GROWS * SAW];   // packed split-bf16 A
    __shared__ float sAB[128];                 // a[64], b[64]
    const int tid = threadIdx.x;

    if (tid < 64) {
        float a = 1.f, b = 0.f;
        if (prevStats) {
            const float invN = 1.0f / (float)NN;
            const float mean = prevStats[tid] * invN;
            const float var  = prevStats[64 + tid] * invN - mean * mean;
            const float inv  = rsqrtf(var + BN_EPS);
            a = inv * prevGamma[tid];
            b = prevBeta[tid] - mean * a;
        }
        sAB[tid]      = a;
        sAB[64 + tid] = b;
    }
    __syncthreads();

    const int row0 = blockIdx.x * GROWS;
    for (int i = tid; i < GROWS * 16; i += 256) {
        const int row = i >> 4;
        const int k4  = (i & 15) * 4;
        float4 x = make_float4(0.f, 0.f, 0.f, 0.f);
        if (row0 + row < NN)
            x = *(const float4*)(Hin + (size_t)(row0 + row) * DD + k4);
        const float xs[4] = {x.x, x.y, x.z, x.w};
        unsigned int* dst = &sA[row * SAW + k4];
#pragma unroll
        for (int j = 0; j < 4; j++) {
            const float xv = fmaf(xs[j], sAB[k4 + j], sAB[64 + k4 + j]);
            short hs, ls;
            split_bf16(xv, hs, ls);
            dst[j] = ((unsigned int)(unsigned short)hs << 16) | (unsigned short)ls;
        }
    }

    const int wave = tid >> 6;    // column tile 0..3
    const int lane = tid & 63;
    const int n15  = lane & 15;
    const int g    = lane >> 4;   // quad
    const int col  = wave * 16 + n15;

    const float* Wm[4] = {Wk, Wq, Wv, Ws};
    bf16x8 wh[4][2], wl[4][2];
#pragma unroll
    for (int m = 0; m < 4; m++) {
#pragma unroll
        for (int c = 0; c < 2; c++) {
            bf16x8 h, l;
#pragma unroll
            for (int j = 0; j < 8; j++) {
                const int k = g * 8 + j + 32 * c;
                short hs, ls;
                split_bf16(Wm[m][k * DD + col], hs, ls);
                h[j] = hs; l[j] = ls;
            }
            wh[m][c] = h; wl[m][c] = l;
        }
    }

    const float bkc = bk[col], bqc = bq[col], bvc = bv[col], bsc = bs[col];
    __syncthreads();

#pragma unroll 1
    for (int t = 0; t < GT; t++) {
        const int rowbase = row0 + t * 16;
        if (rowbase >= NN) break;   // NN % 16 == 0

        bf16x8 ah[2], al[2];
#pragma unroll
        for (int c = 0; c < 2; c++) {
            const uint4 u0 = *(const uint4*)&sA[(t * 16 + n15) * SAW + g * 8 + 32 * c];
            const uint4 u1 = *(const uint4*)&sA[(t * 16 + n15) * SAW + g * 8 + 32 * c + 4];
            const unsigned int us[8] = {u0.x, u0.y, u0.z, u0.w, u1.x, u1.y, u1.z, u1.w};
            bf16x8 h, l;
#pragma unroll
            for (int j = 0; j < 8; j++) {
                h[j] = (short)(us[j] >> 16);
                l[j] = (short)(us[j] & 0xFFFFu);
            }
            ah[c] = h; al[c] = l;
        }

        f32x4 acc[4];
#pragma unroll
        for (int m = 0; m < 4; m++) acc[m] = (f32x4){0.f, 0.f, 0.f, 0.f};

#pragma unroll
        for (int c = 0; c < 2; c++) {
#pragma unroll
            for (int m = 0; m < 4; m++) {
                acc[m] = __builtin_amdgcn_mfma_f32_16x16x32_bf16(ah[c], wh[m][c], acc[m], 0, 0, 0);
                acc[m] = __builtin_amdgcn_mfma_f32_16x16x32_bf16(al[c], wh[m][c], acc[m], 0, 0, 0);
                acc[m] = __builtin_amdgcn_mfma_f32_16x16x32_bf16(ah[c], wl[m][c], acc[m], 0, 0, 0);
            }
        }

#pragma unroll
        for (int r = 0; r < 4; r++) {
            const int row = rowbase + g * 4 + r;
            const size_t o = (size_t)row * DD + col;
            K[o]   = acc[0][r] + bkc;
            QVp[o] = pack_bf16x2(acc[1][r] + bqc, acc[2][r] + bvc);
            OUT[o] = acc[3][r] + bsc;
        }
    }
}

// ---------------------------------------------------------------------------
// CSR build: histogram of dst, two-level exclusive scan, scatter fill.
// ---------------------------------------------------------------------------
__global__ __launch_bounds__(256) void deg_kernel(
    const int* __restrict__ ei, int* __restrict__ deg)
{
    const int e = blockIdx.x * 256 + threadIdx.x;
    if (e < NE) atomicAdd(&deg[ei[NE + e]], 1);
}

__global__ __launch_bounds__(256) void scan_partial_kernel(
    const int* __restrict__ deg, int* __restrict__ psums)
{
    __shared__ int ls[256];
    const int i = blockIdx.x * 256 + threadIdx.x;
    ls[threadIdx.x] = (i < NN) ? deg[i] : 0;
    __syncthreads();
    for (int off = 128; off > 0; off >>= 1) {
        if (threadIdx.x < off) ls[threadIdx.x] += ls[threadIdx.x + off];
        __syncthreads();
    }
    if (threadIdx.x == 0) psums[blockIdx.x] = ls[0];
}

__global__ void scan_offsets_kernel(int* __restrict__ psums, int* __restrict__ rowst)
{
    if (threadIdx.x == 0) {
        int running = 0;
        for (int i = 0; i < NCHUNK; i++) {
            int t = psums[i];
            psums[i] = running;
            running += t;
        }
        rowst[NN] = running;  // == NE
    }
}

__global__ __launch_bounds__(256) void scan_final_kernel(
    const int* __restrict__ deg, const int* __restrict__ psums,
    int* __restrict__ rowst, int* __restrict__ cursor)
{
    __shared__ int ls[256];
    const int i = blockIdx.x * 256 + threadIdx.x;
    const int x = (i < NN) ? deg[i] : 0;
    ls[threadIdx.x] = x;
    __syncthreads();
    for (int off = 1; off < 256; off <<= 1) {
        int v = (threadIdx.x >= off) ? ls[threadIdx.x - off] : 0;
        __syncthreads();
        ls[threadIdx.x] += v;
        __syncthreads();
    }
    if (i < NN) {
        const int excl = psums[blockIdx.x] + ls[threadIdx.x] - x;
        rowst[i]  = excl;
        cursor[i] = excl;
    }
}

__global__ __launch_bounds__(256) void fill_kernel(
    const int* __restrict__ ei, int* __restrict__ cursor, int* __restrict__ csr)
{
    const int e = blockIdx.x * 256 + threadIdx.x;
    if (e < NE) {
        const int src = ei[e];
        const int dst = ei[NE + e];
        csr[atomicAdd(&cursor[dst], 1)] = src;
    }
}

// ---------------------------------------------------------------------------
// Sort each dst's adjacency by src (insertion sort in LDS) AND emit phase
// boundaries pb[n*3+p] = absolute CSR index of first edge with
// src >= (p+1)*PBOUND. Overflow lists (deg>SORT_CAP) left unsorted with
// pb=e0 (all edges swept in the final phase -> correct, just unphased).
// ---------------------------------------------------------------------------
__global__ __launch_bounds__(256) void sortadj_kernel(
    const int* __restrict__ rowst, int* __restrict__ csr, int* __restrict__ pb)
{
    __shared__ int buf[256][SORT_CAP];   // 48 KB
    const int n = blockIdx.x * 256 + threadIdx.x;
    if (n >= NN) return;
    const int e0 = rowst[n], e1 = rowst[n + 1];
    const int d = e1 - e0;
    if (d > SORT_CAP) {
        pb[n * 3 + 0] = e0; pb[n * 3 + 1] = e0; pb[n * 3 + 2] = e0;
        return;
    }
    int* b = buf[threadIdx.x];
    for (int i = 0; i < d; i++) b[i] = csr[e0 + i];
    for (int i = 1; i < d; i++) {
        const int key = b[i];
        int j = i - 1;
        while (j >= 0 && b[j] > key) { b[j + 1] = b[j]; j--; }
        b[j + 1] = key;
    }
    for (int i = 0; i < d; i++) csr[e0 + i] = b[i];
    int idx = 0;
#pragma unroll
    for (int p = 0; p < 3; p++) {
        const int bound = (p + 1) * PBOUND;
        while (idx < d && b[idx] < bound) idx++;
        pb[n * 3 + p] = e0 + idx;
    }
}

// ---------------------------------------------------------------------------
// Phased gather with precomputed boundaries: wave owns NPW consecutive dst
// nodes (lane = column). All waves sweep the same src-partition per phase
// (QVp slice ~3.2 MB -> L2-resident). Per node per phase the edge range is
// KNOWN -> masked unroll-4 batches keep 4 independent loads in flight.
// H = relu(H_skip + acc) in place + fused BN stats.
// ---------------------------------------------------------------------------
__global__ __launch_bounds__(256) void gather_kernel(
    const int* __restrict__ rowst, const int* __restrict__ csr,
    const int* __restrict__ pb,
    const float* __restrict__ K, const unsigned int* __restrict__ QVp,
    float* H, float* __restrict__ stats)
{
    const int tid  = threadIdx.x;
    const int wv   = tid >> 6;
    const int c    = tid & 63;
    const int base = (blockIdx.x * 4 + wv) * NPW;

    float k[NPW], acc[NPW];
    int cur[NPW], end[NPW];
#pragma unroll
    for (int i = 0; i < NPW; i++) {
        const int n = base + i;
        acc[i] = 0.f;
        if (n < NN) {
            k[i]   = K[(size_t)n * DD + c];
            cur[i] = rowst[n];
            end[i] = rowst[n + 1];
        } else {
            k[i] = 0.f; cur[i] = 0; end[i] = 0;
        }
    }

#pragma unroll
    for (int p = 0; p < PHASES; p++) {
#pragma unroll
        for (int i = 0; i < NPW; i++) {
            const int n = base + i;
            if (n >= NN) continue;
            const int pe = (p < PHASES - 1) ? pb[n * 3 + p] : end[i];
            int cu = cur[i];
            const float kk = k[i];
            float a = acc[i];
            while (cu < pe) {                    // trip count known at entry
                const int last = pe - 1;
                const int j1 = min(cu + 1, last);
                const int j2 = min(cu + 2, last);
                const int j3 = min(cu + 3, last);
                const int s0 = csr[cu], s1 = csr[j1], s2 = csr[j2], s3 = csr[j3];
                const unsigned p0 = QVp[(size_t)s0 * DD + c];
                const unsigned p1 = QVp[(size_t)s1 * DD + c];
                const unsigned p2 = QVp[(size_t)s2 * DD + c];
                const unsigned p3 = QVp[(size_t)s3 * DD + c];
                a = gate_fma(kk, p0, a);
                if (cu + 1 <= last) a = gate_fma(kk, p1, a);
                if (cu + 2 <= last) a = gate_fma(kk, p2, a);
                if (cu + 3 <= last) a = gate_fma(kk, p3, a);
                cu += 4;
            }
            acc[i] = a;
            cur[i] = pe;
        }
    }

    float ssum = 0.f, ssq = 0.f;
#pragma unroll
    for (int i = 0; i < NPW; i++) {
        const int n = base + i;
        if (n < NN) {
            const float o = fmaxf(H[(size_t)n * DD + c] + acc[i], 0.f);
            H[(size_t)n * DD + c] = o;
            ssum += o;
            ssq  += o * o;
        }
    }

    __shared__ float ls[256], ls2[256];
    ls[tid]  = ssum;
    ls2[tid] = ssq;
    __syncthreads();
    if (tid < 64) {
        const float a = ls[tid]  + ls[tid + 64]  + ls[tid + 128]  + ls[tid + 192];
        const float b = ls2[tid] + ls2[tid + 64] + ls2[tid + 128] + ls2[tid + 192];
        atomicAdd(&stats[c], a);
        atomicAdd(&stats[64 + c], b);
    }
}

// ---------------------------------------------------------------------------
// Pooled segment-sum (batch sorted -> run-length accumulate, flush on change).
// ---------------------------------------------------------------------------
#define POOL_ROWS 196
__global__ __launch_bounds__(64) void pool_kernel(
    const float* __restrict__ H, const int* __restrict__ batch,
    float* __restrict__ psum, float* __restrict__ pcnt)
{
    const int c  = threadIdx.x;
    const int r0 = blockIdx.x * POOL_ROWS;
    if (r0 >= NN) return;
    const int r1 = min(r0 + POOL_ROWS, NN);

    int cur = batch[r0];
    float acc = 0.f, cnt = 0.f;
    for (int r = r0; r < r1; r++) {
        const int g = batch[r];
        if (g != cur) {
            atomicAdd(&psum[cur * DD + c], acc);
            if (c == 0) atomicAdd(&pcnt[cur], cnt);
            acc = 0.f; cnt = 0.f; cur = g;
        }
        acc += H[(size_t)r * DD + c];
        cnt += 1.f;
    }
    atomicAdd(&psum[cur * DD + c], acc);
    if (c == 0) atomicAdd(&pcnt[cur], cnt);
}

// ---------------------------------------------------------------------------
// Final: pooled mean -> (folded last-layer BN affine) -> logits -> softmax.
// ---------------------------------------------------------------------------
__global__ __launch_bounds__(256) void final_kernel(
    const float* __restrict__ psum, const float* __restrict__ pcnt,
    const float* __restrict__ stats,
    const float* __restrict__ gamma, const float* __restrict__ beta,
    const float* __restrict__ Wlin, const float* __restrict__ blin,
    float* __restrict__ out)
{
    const int g = blockIdx.x * blockDim.x + threadIdx.x;
    if (g >= NG) return;

    const float invc = 1.0f / fmaxf(pcnt[g], 1.0f);
    const float invN = 1.0f / (float)NN;
    float p[DD];
#pragma unroll
    for (int d = 0; d < DD; d++) {
        const float mean = stats[d] * invN;
        const float var  = stats[64 + d] * invN - mean * mean;
        const float inv  = rsqrtf(var + BN_EPS);
        const float a = inv * gamma[d];
        const float b = beta[d] - mean * a;
        p[d] = fmaf(psum[g * DD + d] * invc, a, b);
    }

    float logits[NC];
    float m = -1e30f;
#pragma unroll
    for (int c = 0; c < NC; c++) {
        float acc = blin[c];
#pragma unroll
        for (int d = 0; d < DD; d++) acc = fmaf(p[d], Wlin[d * NC + c], acc);
        logits[c] = acc;
        m = fmaxf(m, acc);
    }
    float sum = 0.f;
#pragma unroll
    for (int c = 0; c < NC; c++) {
        logits[c] = __expf(logits[c] - m);
        sum += logits[c];
    }
    const float inv = 1.f / sum;
#pragma unroll
    for (int c = 0; c < NC; c++) out[g * NC + c] = logits[c] * inv;
}

// ---------------------------------------------------------------------------
extern "C" void kernel_launch(void* const* d_in, const int* in_sizes, int n_in,
                              void* d_out, int out_size, void* d_ws, size_t ws_size,
                              hipStream_t stream)
{
    const float* X     = (const float*)d_in[0];
    const int*   ei    = (const int*)d_in[1];
    const int*   batch = (const int*)d_in[2];
    const float* Wk    = (const float*)d_in[3];
    const float* Wq    = (const float*)d_in[4];
    const float* Wv    = (const float*)d_in[5];
    const float* Ws    = (const float*)d_in[6];
    const float* bk    = (const float*)d_in[7];
    const float* bq    = (const float*)d_in[8];
    const float* bv    = (const float*)d_in[9];
    const float* bconv = (const float*)d_in[10];
    const float* gamma = (const float*)d_in[11];
    const float* beta  = (const float*)d_in[12];
    const float* Wlin  = (const float*)d_in[13];
    const float* blin  = (const float*)d_in[14];
    float* out = (float*)d_out;

    float* ws = (float*)d_ws;
    const size_t M = (size_t)NN * DD;
    float*        K     = ws;                       // M
    unsigned int* QVp   = (unsigned int*)(K + M);   // M (packed bf16 q|v)
    float*        H0    = (float*)(QVp + M);        // M
    float*        H1    = H0 + M;                   // M (gemm ping-pong)
    // --- contiguous zero-init region ---
    int*   deg   = (int*)(H1 + M);                  // NN
    float* psum  = (float*)(deg + NN);              // NG*DD
    float* pcnt  = psum + (size_t)NG * DD;          // NG
    float* stats = pcnt + NG;                       // NL*128
    // --- end zero region ---
    int* rowst  = (int*)(stats + NL * 128);         // NN+1
    int* cursor = rowst + NN + 1;                   // NN
    int* psums  = cursor + NN;                      // 256
    int* csr    = psums + 256;                      // NE
    int* pb     = csr + NE;                         // 3*NN

    const size_t zero_bytes = (size_t)(NN + NG * DD + NG + NL * 128) * sizeof(float);
    hipMemsetAsync(deg, 0, zero_bytes, stream);

    // ---- CSR build + src-sort + phase boundaries ----
    deg_kernel<<<(NE + 255) / 256, 256, 0, stream>>>(ei, deg);
    scan_partial_kernel<<<NCHUNK, 256, 0, stream>>>(deg, psums);
    scan_offsets_kernel<<<1, 64, 0, stream>>>(psums, rowst);
    scan_final_kernel<<<NCHUNK, 256, 0, stream>>>(deg, psums, rowst, cursor);
    fill_kernel<<<(NE + 255) / 256, 256, 0, stream>>>(ei, cursor, csr);
    sortadj_kernel<<<NCHUNK, 256, 0, stream>>>(rowst, csr, pb);

    // ---- layers (BN folded into next GEMM / final) ----
    const float* hin = X;
    for (int l = 0; l < NL; l++) {
        float* hout = (l & 1) ? H1 : H0;
        const float* pS = l ? stats + (l - 1) * 128 : nullptr;
        const float* pG = l ? gamma + (l - 1) * 64  : nullptr;
        const float* pB = l ? beta  + (l - 1) * 64  : nullptr;
        gemm4_mfma<<<(NN + GROWS - 1) / GROWS, 256, 0, stream>>>(
            hin, Wk + l * 4096, Wq + l * 4096, Wv + l * 4096, Ws + l * 4096,
            bk + l * 64, bq + l * 64, bv + l * 64, bconv + l * 64,
            pS, pG, pB, K, QVp, hout);
        gather_kernel<<<(NN + 4 * NPW - 1) / (4 * NPW), 256, 0, stream>>>(
            rowst, csr, pb, K, QVp, hout, stats + l * 128);
        hin = hout;
    }

    pool_kernel<<<(NN + POOL_ROWS - 1) / POOL_ROWS, 64, 0, stream>>>(hin, batch, psum, pcnt);
    final_kernel<<<1, 256, 0, stream>>>(
        psum, pcnt, stats + 4 * 128, gamma + 4 * 64, beta + 4 * 64, Wlin, blin, out);
}

// Round 10
// 761.377 us; speedup vs baseline: 1.4218x; 1.4218x over previous
//
#include <hip/hip_runtime.h>

#define NN 50000
#define NE 800000
#define DD 64
#define NL 5
#define NG 256
#define NC 10
#define BN_EPS 1e-5f
#define NCHUNK ((NN + 255) / 256)   // 196
#define GROWS 64                     // rows per gemm block
#define GT (GROWS / 16)              // 16-row tiles per block
#define SAW 68                       // staged-A row stride (uints): 2-way conflicts only
#define SORT_CAP 48                  // max degree sorted (Poisson(16): P(>48)~0)

typedef __attribute__((ext_vector_type(8))) short bf16x8;
typedef __attribute__((ext_vector_type(4))) float f32x4;

// Pack two floats as bf16 (RNE) into one uint: low16 = q, high16 = v.
__device__ inline unsigned int pack_bf16x2(float q, float v) {
    unsigned int uq = __float_as_uint(q);
    unsigned int uv = __float_as_uint(v);
    uq += 0x7FFFu + ((uq >> 16) & 1u);
    uv += 0x7FFFu + ((uv >> 16) & 1u);
    return (uv & 0xFFFF0000u) | (uq >> 16);
}

// Split fp32 into bf16 hi (RTZ) + bf16 lo (residual). hi+lo ~ x to ~2^-17.
__device__ inline void split_bf16(float x, short& h, short& l) {
    const unsigned u  = __float_as_uint(x);
    const unsigned hb = u & 0xFFFF0000u;
    h = (short)(hb >> 16);
    const float lo = x - __uint_as_float(hb);
    l = (short)(__float_as_uint(lo) >> 16);
}

// gate-fma for one packed bf16 q|v edge value.
// sigmoid via v_exp + v_rcp (fast rcp ~1ulp; budget is 2.6e-3, noise 4.9e-4).
__device__ inline float gate_fma(float k, unsigned p, float acc) {
    const float q = __uint_as_float(p << 16);
    const float v = __uint_as_float(p & 0xFFFF0000u);
    const float e = __expf(-(k + q));
    return fmaf(__builtin_amdgcn_rcpf(1.f + e), v, acc);
}

// ---------------------------------------------------------------------------
// MFMA gemm4 (unchanged): K/Q/V/S = BN(Hin) @ W* + b*. Split-bf16, 3 MFMAs
// per 16x16x32 product, fp32 accumulate. BN of previous layer folded.
// ---------------------------------------------------------------------------
__global__ __launch_bounds__(256) void gemm4_mfma(
    const float* __restrict__ Hin,
    const float* __restrict__ Wk, const float* __restrict__ Wq,
    const float* __restrict__ Wv, const float* __restrict__ Ws,
    const float* __restrict__ bk, const float* __restrict__ bq,
    const float* __restrict__ bv, const float* __restrict__ bs,
    const float* __restrict__ prevStats,   // null for layer 0
    const float* __restrict__ prevGamma, const float* __restrict__ prevBeta,
    float* __restrict__ K, unsigned int* __restrict__ QVp,
    float* __restrict__ OUT)
{
    __shared__ unsigned int sA[GROWS * SAW];   // packed split-bf16 A
    __shared__ float sAB[128];                 // a[64], b[64]
    const int tid = threadIdx.x;

    if (tid < 64) {
        float a = 1.f, b = 0.f;
        if (prevStats) {
            const float invN = 1.0f / (float)NN;
            const float mean = prevStats[tid] * invN;
            const float var  = prevStats[64 + tid] * invN - mean * mean;
            const float inv  = rsqrtf(var + BN_EPS);
            a = inv * prevGamma[tid];
            b = prevBeta[tid] - mean * a;
        }
        sAB[tid]      = a;
        sAB[64 + tid] = b;
    }
    __syncthreads();

    const int row0 = blockIdx.x * GROWS;
    for (int i = tid; i < GROWS * 16; i += 256) {
        const int row = i >> 4;
        const int k4  = (i & 15) * 4;
        float4 x = make_float4(0.f, 0.f, 0.f, 0.f);
        if (row0 + row < NN)
            x = *(const float4*)(Hin + (size_t)(row0 + row) * DD + k4);
        const float xs[4] = {x.x, x.y, x.z, x.w};
        unsigned int* dst = &sA[row * SAW + k4];
#pragma unroll
        for (int j = 0; j < 4; j++) {
            const float xv = fmaf(xs[j], sAB[k4 + j], sAB[64 + k4 + j]);
            short hs, ls;
            split_bf16(xv, hs, ls);
            dst[j] = ((unsigned int)(unsigned short)hs << 16) | (unsigned short)ls;
        }
    }

    const int wave = tid >> 6;    // column tile 0..3
    const int lane = tid & 63;
    const int n15  = lane & 15;
    const int g    = lane >> 4;   // quad
    const int col  = wave * 16 + n15;

    const float* Wm[4] = {Wk, Wq, Wv, Ws};
    bf16x8 wh[4][2], wl[4][2];
#pragma unroll
    for (int m = 0; m < 4; m++) {
#pragma unroll
        for (int c = 0; c < 2; c++) {
            bf16x8 h, l;
#pragma unroll
            for (int j = 0; j < 8; j++) {
                const int k = g * 8 + j + 32 * c;
                short hs, ls;
                split_bf16(Wm[m][k * DD + col], hs, ls);
                h[j] = hs; l[j] = ls;
            }
            wh[m][c] = h; wl[m][c] = l;
        }
    }

    const float bkc = bk[col], bqc = bq[col], bvc = bv[col], bsc = bs[col];
    __syncthreads();

#pragma unroll 1
    for (int t = 0; t < GT; t++) {
        const int rowbase = row0 + t * 16;
        if (rowbase >= NN) break;   // NN % 16 == 0

        bf16x8 ah[2], al[2];
#pragma unroll
        for (int c = 0; c < 2; c++) {
            const uint4 u0 = *(const uint4*)&sA[(t * 16 + n15) * SAW + g * 8 + 32 * c];
            const uint4 u1 = *(const uint4*)&sA[(t * 16 + n15) * SAW + g * 8 + 32 * c + 4];
            const unsigned int us[8] = {u0.x, u0.y, u0.z, u0.w, u1.x, u1.y, u1.z, u1.w};
            bf16x8 h, l;
#pragma unroll
            for (int j = 0; j < 8; j++) {
                h[j] = (short)(us[j] >> 16);
                l[j] = (short)(us[j] & 0xFFFFu);
            }
            ah[c] = h; al[c] = l;
        }

        f32x4 acc[4];
#pragma unroll
        for (int m = 0; m < 4; m++) acc[m] = (f32x4){0.f, 0.f, 0.f, 0.f};

#pragma unroll
        for (int c = 0; c < 2; c++) {
#pragma unroll
            for (int m = 0; m < 4; m++) {
                acc[m] = __builtin_amdgcn_mfma_f32_16x16x32_bf16(ah[c], wh[m][c], acc[m], 0, 0, 0);
                acc[m] = __builtin_amdgcn_mfma_f32_16x16x32_bf16(al[c], wh[m][c], acc[m], 0, 0, 0);
                acc[m] = __builtin_amdgcn_mfma_f32_16x16x32_bf16(ah[c], wl[m][c], acc[m], 0, 0, 0);
            }
        }

#pragma unroll
        for (int r = 0; r < 4; r++) {
            const int row = rowbase + g * 4 + r;
            const size_t o = (size_t)row * DD + col;
            K[o]   = acc[0][r] + bkc;
            QVp[o] = pack_bf16x2(acc[1][r] + bqc, acc[2][r] + bvc);
            OUT[o] = acc[3][r] + bsc;
        }
    }
}

// ---------------------------------------------------------------------------
// CSR build: histogram of dst, two-level exclusive scan, scatter fill.
// ---------------------------------------------------------------------------
__global__ __launch_bounds__(256) void deg_kernel(
    const int* __restrict__ ei, int* __restrict__ deg)
{
    const int e = blockIdx.x * 256 + threadIdx.x;
    if (e < NE) atomicAdd(&deg[ei[NE + e]], 1);
}

__global__ __launch_bounds__(256) void scan_partial_kernel(
    const int* __restrict__ deg, int* __restrict__ psums)
{
    __shared__ int ls[256];
    const int i = blockIdx.x * 256 + threadIdx.x;
    ls[threadIdx.x] = (i < NN) ? deg[i] : 0;
    __syncthreads();
    for (int off = 128; off > 0; off >>= 1) {
        if (threadIdx.x < off) ls[threadIdx.x] += ls[threadIdx.x + off];
        __syncthreads();
    }
    if (threadIdx.x == 0) psums[blockIdx.x] = ls[0];
}

__global__ void scan_offsets_kernel(int* __restrict__ psums, int* __restrict__ rowst)
{
    if (threadIdx.x == 0) {
        int running = 0;
        for (int i = 0; i < NCHUNK; i++) {
            int t = psums[i];
            psums[i] = running;
            running += t;
        }
        rowst[NN] = running;  // == NE
    }
}

__global__ __launch_bounds__(256) void scan_final_kernel(
    const int* __restrict__ deg, const int* __restrict__ psums,
    int* __restrict__ rowst, int* __restrict__ cursor)
{
    __shared__ int ls[256];
    const int i = blockIdx.x * 256 + threadIdx.x;
    const int x = (i < NN) ? deg[i] : 0;
    ls[threadIdx.x] = x;
    __syncthreads();
    for (int off = 1; off < 256; off <<= 1) {
        int v = (threadIdx.x >= off) ? ls[threadIdx.x - off] : 0;
        __syncthreads();
        ls[threadIdx.x] += v;
        __syncthreads();
    }
    if (i < NN) {
        const int excl = psums[blockIdx.x] + ls[threadIdx.x] - x;
        rowst[i]  = excl;
        cursor[i] = excl;
    }
}

__global__ __launch_bounds__(256) void fill_kernel(
    const int* __restrict__ ei, int* __restrict__ cursor, int* __restrict__ csr)
{
    const int e = blockIdx.x * 256 + threadIdx.x;
    if (e < NE) {
        const int src = ei[e];
        const int dst = ei[NE + e];
        csr[atomicAdd(&cursor[dst], 1)] = src;
    }
}

// ---------------------------------------------------------------------------
// Sort each dst's adjacency by src (insertion sort in LDS). Pure locality
// optimization: co-scheduled waves then sweep src-space in a correlated
// moving window (gather is order-independent -> always correct).
// ---------------------------------------------------------------------------
__global__ __launch_bounds__(256) void sortadj_kernel(
    const int* __restrict__ rowst, int* __restrict__ csr)
{
    __shared__ int buf[256][SORT_CAP];   // 48 KB
    const int n = blockIdx.x * 256 + threadIdx.x;
    if (n >= NN) return;
    const int e0 = rowst[n], e1 = rowst[n + 1];
    const int d = e1 - e0;
    if (d <= 1 || d > SORT_CAP) return;  // >CAP: leave unsorted (still correct)
    int* b = buf[threadIdx.x];
    for (int i = 0; i < d; i++) b[i] = csr[e0 + i];
    for (int i = 1; i < d; i++) {
        const int key = b[i];
        int j = i - 1;
        while (j >= 0 && b[j] > key) { b[j + 1] = b[j]; j--; }
        b[j + 1] = key;
    }
    for (int i = 0; i < d; i++) csr[e0 + i] = b[i];
}

// ---------------------------------------------------------------------------
// Gather (R5 structure): one 64-lane wave per dst node, unroll-4 edge loop
// (4 independent QVp loads in flight). Sorted adjacency gives an implicit
// src-sweep across co-resident waves. 32-bit indexing for saddr+voffset
// loads. H = relu(H_skip + acc) in place + fused BN stats.
// ---------------------------------------------------------------------------
#define GATHER_BLOCKS 2048
__global__ __launch_bounds__(256) void gather_kernel(
    const int* __restrict__ rowst, const int* __restrict__ csr,
    const float* __restrict__ K, const unsigned int* __restrict__ QVp,
    float* H, float* __restrict__ stats)
{
    const int c  = threadIdx.x & 63;
    const int rg = threadIdx.x >> 6;
    float s = 0.f, s2 = 0.f;

    for (int n = blockIdx.x * 4 + rg; n < NN; n += GATHER_BLOCKS * 4) {
        const unsigned rowoff = (unsigned)(n * DD + c);
        const float k     = K[rowoff];
        const float hskip = H[rowoff];
        const int e0 = rowst[n], e1 = rowst[n + 1];
        float acc = 0.f;
        int i = e0;
        for (; i + 4 <= e1; i += 4) {
            const int s0 = csr[i], s1 = csr[i + 1], s2i = csr[i + 2], s3 = csr[i + 3];
            const unsigned p0 = QVp[(unsigned)(s0  * DD + c)];
            const unsigned p1 = QVp[(unsigned)(s1  * DD + c)];
            const unsigned p2 = QVp[(unsigned)(s2i * DD + c)];
            const unsigned p3 = QVp[(unsigned)(s3  * DD + c)];
            acc = gate_fma(k, p0, acc);
            acc = gate_fma(k, p1, acc);
            acc = gate_fma(k, p2, acc);
            acc = gate_fma(k, p3, acc);
        }
        for (; i < e1; i++) {
            const unsigned p0 = QVp[(unsigned)(csr[i] * DD + c)];
            acc = gate_fma(k, p0, acc);
        }
        const float o = fmaxf(hskip + acc, 0.f);
        H[rowoff] = o;
        s += o;
        s2 += o * o;
    }

    __shared__ float ls[256], ls2[256];
    ls[threadIdx.x]  = s;
    ls2[threadIdx.x] = s2;
    __syncthreads();
    if (threadIdx.x < 64) {
        s  = ls[threadIdx.x]  + ls[threadIdx.x + 64]  + ls[threadIdx.x + 128]  + ls[threadIdx.x + 192];
        s2 = ls2[threadIdx.x] + ls2[threadIdx.x + 64] + ls2[threadIdx.x + 128] + ls2[threadIdx.x + 192];
        atomicAdd(&stats[c], s);
        atomicAdd(&stats[64 + c], s2);
    }
}

// ---------------------------------------------------------------------------
// Pooled segment-sum (batch sorted -> run-length accumulate, flush on change).
// ---------------------------------------------------------------------------
#define POOL_ROWS 196
__global__ __launch_bounds__(64) void pool_kernel(
    const float* __restrict__ H, const int* __restrict__ batch,
    float* __restrict__ psum, float* __restrict__ pcnt)
{
    const int c  = threadIdx.x;
    const int r0 = blockIdx.x * POOL_ROWS;
    if (r0 >= NN) return;
    const int r1 = min(r0 + POOL_ROWS, NN);

    int cur = batch[r0];
    float acc = 0.f, cnt = 0.f;
    for (int r = r0; r < r1; r++) {
        const int g = batch[r];
        if (g != cur) {
            atomicAdd(&psum[cur * DD + c], acc);
            if (c == 0) atomicAdd(&pcnt[cur], cnt);
            acc = 0.f; cnt = 0.f; cur = g;
        }
        acc += H[(size_t)r * DD + c];
        cnt += 1.f;
    }
    atomicAdd(&psum[cur * DD + c], acc);
    if (c == 0) atomicAdd(&pcnt[cur], cnt);
}

// ---------------------------------------------------------------------------
// Final: pooled mean -> (folded last-layer BN affine) -> logits -> softmax.
// ---------------------------------------------------------------------------
__global__ __launch_bounds__(256) void final_kernel(
    const float* __restrict__ psum, const float* __restrict__ pcnt,
    const float* __restrict__ stats,
    const float* __restrict__ gamma, const float* __restrict__ beta,
    const float* __restrict__ Wlin, const float* __restrict__ blin,
    float* __restrict__ out)
{
    const int g = blockIdx.x * blockDim.x + threadIdx.x;
    if (g >= NG) return;

    const float invc = 1.0f / fmaxf(pcnt[g], 1.0f);
    const float invN = 1.0f / (float)NN;
    float p[DD];
#pragma unroll
    for (int d = 0; d < DD; d++) {
        const float mean = stats[d] * invN;
        const float var  = stats[64 + d] * invN - mean * mean;
        const float inv  = rsqrtf(var + BN_EPS);
        const float a = inv * gamma[d];
        const float b = beta[d] - mean * a;
        p[d] = fmaf(psum[g * DD + d] * invc, a, b);
    }

    float logits[NC];
    float m = -1e30f;
#pragma unroll
    for (int c = 0; c < NC; c++) {
        float acc = blin[c];
#pragma unroll
        for (int d = 0; d < DD; d++) acc = fmaf(p[d], Wlin[d * NC + c], acc);
        logits[c] = acc;
        m = fmaxf(m, acc);
    }
    float sum = 0.f;
#pragma unroll
    for (int c = 0; c < NC; c++) {
        logits[c] = __expf(logits[c] - m);
        sum += logits[c];
    }
    const float inv = 1.f / sum;
#pragma unroll
    for (int c = 0; c < NC; c++) out[g * NC + c] = logits[c] * inv;
}

// ---------------------------------------------------------------------------
extern "C" void kernel_launch(void* const* d_in, const int* in_sizes, int n_in,
                              void* d_out, int out_size, void* d_ws, size_t ws_size,
                              hipStream_t stream)
{
    const float* X     = (const float*)d_in[0];
    const int*   ei    = (const int*)d_in[1];
    const int*   batch = (const int*)d_in[2];
    const float* Wk    = (const float*)d_in[3];
    const float* Wq    = (const float*)d_in[4];
    const float* Wv    = (const float*)d_in[5];
    const float* Ws    = (const float*)d_in[6];
    const float* bk    = (const float*)d_in[7];
    const float* bq    = (const float*)d_in[8];
    const float* bv    = (const float*)d_in[9];
    const float* bconv = (const float*)d_in[10];
    const float* gamma = (const float*)d_in[11];
    const float* beta  = (const float*)d_in[12];
    const float* Wlin  = (const float*)d_in[13];
    const float* blin  = (const float*)d_in[14];
    float* out = (float*)d_out;

    float* ws = (float*)d_ws;
    const size_t M = (size_t)NN * DD;
    float*        K     = ws;                       // M
    unsigned int* QVp   = (unsigned int*)(K + M);   // M (packed bf16 q|v)
    float*        H0    = (float*)(QVp + M);        // M
    float*        H1    = H0 + M;                   // M (gemm ping-pong)
    // --- contiguous zero-init region ---
    int*   deg   = (int*)(H1 + M);                  // NN
    float* psum  = (float*)(deg + NN);              // NG*DD
    float* pcnt  = psum + (size_t)NG * DD;          // NG
    float* stats = pcnt + NG;                       // NL*128
    // --- end zero region ---
    int* rowst  = (int*)(stats + NL * 128);         // NN+1
    int* cursor = rowst + NN + 1;                   // NN
    int* psums  = cursor + NN;                      // 256
    int* csr    = psums + 256;                      // NE

    const size_t zero_bytes = (size_t)(NN + NG * DD + NG + NL * 128) * sizeof(float);
    hipMemsetAsync(deg, 0, zero_bytes, stream);

    // ---- CSR build + src-sort of adjacency lists ----
    deg_kernel<<<(NE + 255) / 256, 256, 0, stream>>>(ei, deg);
    scan_partial_kernel<<<NCHUNK, 256, 0, stream>>>(deg, psums);
    scan_offsets_kernel<<<1, 64, 0, stream>>>(psums, rowst);
    scan_final_kernel<<<NCHUNK, 256, 0, stream>>>(deg, psums, rowst, cursor);
    fill_kernel<<<(NE + 255) / 256, 256, 0, stream>>>(ei, cursor, csr);
    sortadj_kernel<<<NCHUNK, 256, 0, stream>>>(rowst, csr);

    // ---- layers (BN folded into next GEMM / final) ----
    const float* hin = X;
    for (int l = 0; l < NL; l++) {
        float* hout = (l & 1) ? H1 : H0;
        const float* pS = l ? stats + (l - 1) * 128 : nullptr;
        const float* pG = l ? gamma + (l - 1) * 64  : nullptr;
        const float* pB = l ? beta  + (l - 1) * 64  : nullptr;
        gemm4_mfma<<<(NN + GROWS - 1) / GROWS, 256, 0, stream>>>(
            hin, Wk + l * 4096, Wq + l * 4096, Wv + l * 4096, Ws + l * 4096,
            bk + l * 64, bq + l * 64, bv + l * 64, bconv + l * 64,
            pS, pG, pB, K, QVp, hout);
        gather_kernel<<<GATHER_BLOCKS, 256, 0, stream>>>(
            rowst, csr, K, QVp, hout, stats + l * 128);
        hin = hout;
    }

    pool_kernel<<<(NN + POOL_ROWS - 1) / POOL_ROWS, 64, 0, stream>>>(hin, batch, psum, pcnt);
    final_kernel<<<1, 256, 0, stream>>>(
        psum, pcnt, stats + 4 * 128, gamma + 4 * 64, beta + 4 * 64, Wlin, blin, out);
}

// Round 11
// 714.813 us; speedup vs baseline: 1.5144x; 1.0651x over previous
//
#include <hip/hip_runtime.h>

#define NN 50000
#define NE 800000
#define DD 64
#define NL 5
#define NG 256
#define NC 10
#define BN_EPS 1e-5f
#define NCHUNK ((NN + 255) / 256)   // 196
#define GROWS 128                    // rows per gemm block
#define GT (GROWS / 16)              // 16-row tiles per block
#define SAW 68                       // staged-A row stride (uints): 2-way conflicts only

typedef __attribute__((ext_vector_type(8))) short bf16x8;
typedef __attribute__((ext_vector_type(4))) float f32x4;

// Pack two floats as bf16 (RNE) into one uint: low16 = q, high16 = v.
__device__ inline unsigned int pack_bf16x2(float q, float v) {
    unsigned int uq = __float_as_uint(q);
    unsigned int uv = __float_as_uint(v);
    uq += 0x7FFFu + ((uq >> 16) & 1u);
    uv += 0x7FFFu + ((uv >> 16) & 1u);
    return (uv & 0xFFFF0000u) | (uq >> 16);
}

// Split fp32 into bf16 hi (RTZ) + bf16 lo (residual). hi+lo ~ x to ~2^-17.
__device__ inline void split_bf16(float x, short& h, short& l) {
    const unsigned u  = __float_as_uint(x);
    const unsigned hb = u & 0xFFFF0000u;
    h = (short)(hb >> 16);
    const float lo = x - __uint_as_float(hb);
    l = (short)(__float_as_uint(lo) >> 16);
}

// gate-fma for one packed bf16 q|v edge value.
// sigmoid via v_exp + v_rcp (fast rcp ~1ulp; budget 2.6e-3, noise 4.9e-4).
__device__ inline float gate_fma(float k, unsigned p, float acc) {
    const float q = __uint_as_float(p << 16);
    const float v = __uint_as_float(p & 0xFFFF0000u);
    const float e = __expf(-(k + q));
    return fmaf(__builtin_amdgcn_rcpf(1.f + e), v, acc);
}

// ---------------------------------------------------------------------------
// W-fragment prep: split all 5 layers' Wk/Wq/Wv/Ws into bf16 hi/lo fragment
// buffers laid out in EXACT MFMA read order:
//   t = l*2048 + m*512 + c*256 + w*64 + lane  ->  bf16x8 (16 B)
// so gemm loads each fragment with one coalesced dwordx4 per lane.
// ---------------------------------------------------------------------------
__global__ __launch_bounds__(256) void wprep_kernel(
    const float* __restrict__ Wk, const float* __restrict__ Wq,
    const float* __restrict__ Wv, const float* __restrict__ Ws,
    bf16x8* __restrict__ whbuf, bf16x8* __restrict__ wlbuf)
{
    const int t = blockIdx.x * 256 + threadIdx.x;
    if (t >= NL * 4 * 2 * 4 * 64) return;
    const int lane = t & 63;
    const int w    = (t >> 6) & 3;
    const int c    = (t >> 8) & 1;
    const int m    = (t >> 9) & 3;
    const int l    = t >> 11;

    const float* Wm4[4] = {Wk, Wq, Wv, Ws};
    const float* W = Wm4[m] + l * 4096;
    const int col = w * 16 + (lane & 15);
    const int g   = lane >> 4;

    bf16x8 h, lo;
#pragma unroll
    for (int j = 0; j < 8; j++) {
        const int k = g * 8 + j + 32 * c;
        short hs, ls;
        split_bf16(W[k * DD + col], hs, ls);
        h[j] = hs; lo[j] = ls;
    }
    whbuf[t] = h;
    wlbuf[t] = lo;
}

// ---------------------------------------------------------------------------
// MFMA gemm4: K/Q/V/S = BN(Hin) @ W* + b*. Split-bf16, 3 MFMAs per 16x16x32
// product, fp32 accumulate. BN of previous layer folded. A-tile staged once
// per block in LDS as packed split-bf16. W fragments loaded coalesced from
// the wprep buffers (16 x dwordx4 per lane, no in-kernel splits).
// ---------------------------------------------------------------------------
__global__ __launch_bounds__(256) void gemm4_mfma(
    const float* __restrict__ Hin,
    const bf16x8* __restrict__ whbuf, const bf16x8* __restrict__ wlbuf,
    const float* __restrict__ bk, const float* __restrict__ bq,
    const float* __restrict__ bv, const float* __restrict__ bs,
    const float* __restrict__ prevStats,   // null for layer 0
    const float* __restrict__ prevGamma, const float* __restrict__ prevBeta,
    float* __restrict__ K, unsigned int* __restrict__ QVp,
    float* __restrict__ OUT)
{
    __shared__ unsigned int sA[GROWS * SAW];   // 34 KB packed split-bf16 A
    __shared__ float sAB[128];                 // a[64], b[64]
    const int tid = threadIdx.x;

    if (tid < 64) {
        float a = 1.f, b = 0.f;
        if (prevStats) {
            const float invN = 1.0f / (float)NN;
            const float mean = prevStats[tid] * invN;
            const float var  = prevStats[64 + tid] * invN - mean * mean;
            const float inv  = rsqrtf(var + BN_EPS);
            a = inv * prevGamma[tid];
            b = prevBeta[tid] - mean * a;
        }
        sAB[tid]      = a;
        sAB[64 + tid] = b;
    }
    __syncthreads();

    const int row0 = blockIdx.x * GROWS;
    for (int i = tid; i < GROWS * 16; i += 256) {
        const int row = i >> 4;
        const int k4  = (i & 15) * 4;
        float4 x = make_float4(0.f, 0.f, 0.f, 0.f);
        if (row0 + row < NN)
            x = *(const float4*)(Hin + (size_t)(row0 + row) * DD + k4);
        const float xs[4] = {x.x, x.y, x.z, x.w};
        unsigned int* dst = &sA[row * SAW + k4];
#pragma unroll
        for (int j = 0; j < 4; j++) {
            const float xv = fmaf(xs[j], sAB[k4 + j], sAB[64 + k4 + j]);
            short hs, ls;
            split_bf16(xv, hs, ls);
            dst[j] = ((unsigned int)(unsigned short)hs << 16) | (unsigned short)ls;
        }
    }

    const int wave = tid >> 6;    // column tile 0..3
    const int lane = tid & 63;
    const int n15  = lane & 15;
    const int g    = lane >> 4;   // quad
    const int col  = wave * 16 + n15;

    // ---- W fragments: coalesced loads from prep buffers ----
    bf16x8 wh[4][2], wl[4][2];
    {
        const int base = wave * 64 + lane;
#pragma unroll
        for (int m = 0; m < 4; m++)
#pragma unroll
            for (int c = 0; c < 2; c++) {
                const int idx = m * 512 + c * 256 + base;
                wh[m][c] = whbuf[idx];
                wl[m][c] = wlbuf[idx];
            }
    }

    const float bkc = bk[col], bqc = bq[col], bvc = bv[col], bsc = bs[col];
    __syncthreads();

#pragma unroll 1
    for (int t = 0; t < GT; t++) {
        const int rowbase = row0 + t * 16;
        if (rowbase >= NN) break;   // NN % 16 == 0

        bf16x8 ah[2], al[2];
#pragma unroll
        for (int c = 0; c < 2; c++) {
            const uint4 u0 = *(const uint4*)&sA[(t * 16 + n15) * SAW + g * 8 + 32 * c];
            const uint4 u1 = *(const uint4*)&sA[(t * 16 + n15) * SAW + g * 8 + 32 * c + 4];
            const unsigned int us[8] = {u0.x, u0.y, u0.z, u0.w, u1.x, u1.y, u1.z, u1.w};
            bf16x8 h, l;
#pragma unroll
            for (int j = 0; j < 8; j++) {
                h[j] = (short)(us[j] >> 16);
                l[j] = (short)(us[j] & 0xFFFFu);
            }
            ah[c] = h; al[c] = l;
        }

        f32x4 acc[4];
#pragma unroll
        for (int m = 0; m < 4; m++) acc[m] = (f32x4){0.f, 0.f, 0.f, 0.f};

#pragma unroll
        for (int c = 0; c < 2; c++) {
#pragma unroll
            for (int m = 0; m < 4; m++) {
                acc[m] = __builtin_amdgcn_mfma_f32_16x16x32_bf16(ah[c], wh[m][c], acc[m], 0, 0, 0);
                acc[m] = __builtin_amdgcn_mfma_f32_16x16x32_bf16(al[c], wh[m][c], acc[m], 0, 0, 0);
                acc[m] = __builtin_amdgcn_mfma_f32_16x16x32_bf16(ah[c], wl[m][c], acc[m], 0, 0, 0);
            }
        }

#pragma unroll
        for (int r = 0; r < 4; r++) {
            const int row = rowbase + g * 4 + r;
            const size_t o = (size_t)row * DD + col;
            K[o]   = acc[0][r] + bkc;
            QVp[o] = pack_bf16x2(acc[1][r] + bqc, acc[2][r] + bvc);
            OUT[o] = acc[3][r] + bsc;
        }
    }
}

// ---------------------------------------------------------------------------
// CSR build: histogram of dst, two-level exclusive scan, scatter fill.
// ---------------------------------------------------------------------------
__global__ __launch_bounds__(256) void deg_kernel(
    const int* __restrict__ ei, int* __restrict__ deg)
{
    const int e = blockIdx.x * 256 + threadIdx.x;
    if (e < NE) atomicAdd(&deg[ei[NE + e]], 1);
}

__global__ __launch_bounds__(256) void scan_partial_kernel(
    const int* __restrict__ deg, int* __restrict__ psums)
{
    __shared__ int ls[256];
    const int i = blockIdx.x * 256 + threadIdx.x;
    ls[threadIdx.x] = (i < NN) ? deg[i] : 0;
    __syncthreads();
    for (int off = 128; off > 0; off >>= 1) {
        if (threadIdx.x < off) ls[threadIdx.x] += ls[threadIdx.x + off];
        __syncthreads();
    }
    if (threadIdx.x == 0) psums[blockIdx.x] = ls[0];
}

__global__ void scan_offsets_kernel(int* __restrict__ psums, int* __restrict__ rowst)
{
    if (threadIdx.x == 0) {
        int running = 0;
        for (int i = 0; i < NCHUNK; i++) {
            int t = psums[i];
            psums[i] = running;
            running += t;
        }
        rowst[NN] = running;  // == NE
    }
}

__global__ __launch_bounds__(256) void scan_final_kernel(
    const int* __restrict__ deg, const int* __restrict__ psums,
    int* __restrict__ rowst, int* __restrict__ cursor)
{
    __shared__ int ls[256];
    const int i = blockIdx.x * 256 + threadIdx.x;
    const int x = (i < NN) ? deg[i] : 0;
    ls[threadIdx.x] = x;
    __syncthreads();
    for (int off = 1; off < 256; off <<= 1) {
        int v = (threadIdx.x >= off) ? ls[threadIdx.x - off] : 0;
        __syncthreads();
        ls[threadIdx.x] += v;
        __syncthreads();
    }
    if (i < NN) {
        const int excl = psums[blockIdx.x] + ls[threadIdx.x] - x;
        rowst[i]  = excl;
        cursor[i] = excl;
    }
}

__global__ __launch_bounds__(256) void fill_kernel(
    const int* __restrict__ ei, int* __restrict__ cursor, int* __restrict__ csr)
{
    const int e = blockIdx.x * 256 + threadIdx.x;
    if (e < NE) {
        const int src = ei[e];
        const int dst = ei[NE + e];
        csr[atomicAdd(&cursor[dst], 1)] = src;
    }
}

// ---------------------------------------------------------------------------
// Gather (R10, best measured): one 64-lane wave per dst node, unroll-4 edge
// loop (4 independent QVp loads in flight). 32-bit indexing. H = relu(H_skip
// + acc) in place + fused BN stats. At its structural floor: FETCH ~91 MB =
// per-XCD compulsory misses (each XCD touches ~86% of QVp rows).
// ---------------------------------------------------------------------------
#define GATHER_BLOCKS 2048
__global__ __launch_bounds__(256) void gather_kernel(
    const int* __restrict__ rowst, const int* __restrict__ csr,
    const float* __restrict__ K, const unsigned int* __restrict__ QVp,
    float* H, float* __restrict__ stats)
{
    const int c  = threadIdx.x & 63;
    const int rg = threadIdx.x >> 6;
    float s = 0.f, s2 = 0.f;

    for (int n = blockIdx.x * 4 + rg; n < NN; n += GATHER_BLOCKS * 4) {
        const unsigned rowoff = (unsigned)(n * DD + c);
        const float k     = K[rowoff];
        const float hskip = H[rowoff];
        const int e0 = rowst[n], e1 = rowst[n + 1];
        float acc = 0.f;
        int i = e0;
        for (; i + 4 <= e1; i += 4) {
            const int s0 = csr[i], s1 = csr[i + 1], s2i = csr[i + 2], s3 = csr[i + 3];
            const unsigned p0 = QVp[(unsigned)(s0  * DD + c)];
            const unsigned p1 = QVp[(unsigned)(s1  * DD + c)];
            const unsigned p2 = QVp[(unsigned)(s2i * DD + c)];
            const unsigned p3 = QVp[(unsigned)(s3  * DD + c)];
            acc = gate_fma(k, p0, acc);
            acc = gate_fma(k, p1, acc);
            acc = gate_fma(k, p2, acc);
            acc = gate_fma(k, p3, acc);
        }
        for (; i < e1; i++) {
            const unsigned p0 = QVp[(unsigned)(csr[i] * DD + c)];
            acc = gate_fma(k, p0, acc);
        }
        const float o = fmaxf(hskip + acc, 0.f);
        H[rowoff] = o;
        s += o;
        s2 += o * o;
    }

    __shared__ float ls[256], ls2[256];
    ls[threadIdx.x]  = s;
    ls2[threadIdx.x] = s2;
    __syncthreads();
    if (threadIdx.x < 64) {
        s  = ls[threadIdx.x]  + ls[threadIdx.x + 64]  + ls[threadIdx.x + 128]  + ls[threadIdx.x + 192];
        s2 = ls2[threadIdx.x] + ls2[threadIdx.x + 64] + ls2[threadIdx.x + 128] + ls2[threadIdx.x + 192];
        atomicAdd(&stats[c], s);
        atomicAdd(&stats[64 + c], s2);
    }
}

// ---------------------------------------------------------------------------
// Pooled segment-sum (batch sorted -> run-length accumulate, flush on change).
// ---------------------------------------------------------------------------
#define POOL_ROWS 196
__global__ __launch_bounds__(64) void pool_kernel(
    const float* __restrict__ H, const int* __restrict__ batch,
    float* __restrict__ psum, float* __restrict__ pcnt)
{
    const int c  = threadIdx.x;
    const int r0 = blockIdx.x * POOL_ROWS;
    if (r0 >= NN) return;
    const int r1 = min(r0 + POOL_ROWS, NN);

    int cur = batch[r0];
    float acc = 0.f, cnt = 0.f;
    for (int r = r0; r < r1; r++) {
        const int g = batch[r];
        if (g != cur) {
            atomicAdd(&psum[cur * DD + c], acc);
            if (c == 0) atomicAdd(&pcnt[cur], cnt);
            acc = 0.f; cnt = 0.f; cur = g;
        }
        acc += H[(size_t)r * DD + c];
        cnt += 1.f;
    }
    atomicAdd(&psum[cur * DD + c], acc);
    if (c == 0) atomicAdd(&pcnt[cur], cnt);
}

// ---------------------------------------------------------------------------
// Final: pooled mean -> (folded last-layer BN affine) -> logits -> softmax.
// ---------------------------------------------------------------------------
__global__ __launch_bounds__(256) void final_kernel(
    const float* __restrict__ psum, const float* __restrict__ pcnt,
    const float* __restrict__ stats,
    const float* __restrict__ gamma, const float* __restrict__ beta,
    const float* __restrict__ Wlin, const float* __restrict__ blin,
    float* __restrict__ out)
{
    const int g = blockIdx.x * blockDim.x + threadIdx.x;
    if (g >= NG) return;

    const float invc = 1.0f / fmaxf(pcnt[g], 1.0f);
    const float invN = 1.0f / (float)NN;
    float p[DD];
#pragma unroll
    for (int d = 0; d < DD; d++) {
        const float mean = stats[d] * invN;
        const float var  = stats[64 + d] * invN - mean * mean;
        const float inv  = rsqrtf(var + BN_EPS);
        const float a = inv * gamma[d];
        const float b = beta[d] - mean * a;
        p[d] = fmaf(psum[g * DD + d] * invc, a, b);
    }

    float logits[NC];
    float m = -1e30f;
#pragma unroll
    for (int c = 0; c < NC; c++) {
        float acc = blin[c];
#pragma unroll
        for (int d = 0; d < DD; d++) acc = fmaf(p[d], Wlin[d * NC + c], acc);
        logits[c] = acc;
        m = fmaxf(m, acc);
    }
    float sum = 0.f;
#pragma unroll
    for (int c = 0; c < NC; c++) {
        logits[c] = __expf(logits[c] - m);
        sum += logits[c];
    }
    const float inv = 1.f / sum;
#pragma unroll
    for (int c = 0; c < NC; c++) out[g * NC + c] = logits[c] * inv;
}

// ---------------------------------------------------------------------------
extern "C" void kernel_launch(void* const* d_in, const int* in_sizes, int n_in,
                              void* d_out, int out_size, void* d_ws, size_t ws_size,
                              hipStream_t stream)
{
    const float* X     = (const float*)d_in[0];
    const int*   ei    = (const int*)d_in[1];
    const int*   batch = (const int*)d_in[2];
    const float* Wk    = (const float*)d_in[3];
    const float* Wq    = (const float*)d_in[4];
    const float* Wv    = (const float*)d_in[5];
    const float* Ws    = (const float*)d_in[6];
    const float* bk    = (const float*)d_in[7];
    const float* bq    = (const float*)d_in[8];
    const float* bv    = (const float*)d_in[9];
    const float* bconv = (const float*)d_in[10];
    const float* gamma = (const float*)d_in[11];
    const float* beta  = (const float*)d_in[12];
    const float* Wlin  = (const float*)d_in[13];
    const float* blin  = (const float*)d_in[14];
    float* out = (float*)d_out;

    float* ws = (float*)d_ws;
    const size_t M = (size_t)NN * DD;
    float*        K     = ws;                       // M
    unsigned int* QVp   = (unsigned int*)(K + M);   // M (packed bf16 q|v)
    float*        H0    = (float*)(QVp + M);        // M
    float*        H1    = H0 + M;                   // M (gemm ping-pong)
    // --- contiguous zero-init region ---
    int*   deg   = (int*)(H1 + M);                  // NN
    float* psum  = (float*)(deg + NN);              // NG*DD
    float* pcnt  = psum + (size_t)NG * DD;          // NG
    float* stats = pcnt + NG;                       // NL*128
    // --- end zero region ---
    int* rowst  = (int*)(stats + NL * 128);         // NN+1
    int* cursor = rowst + NN + 1;                   // NN
    int* psums  = cursor + NN;                      // 256
    int* csr    = psums + 256;                      // NE
    bf16x8* whbuf = (bf16x8*)(csr + NE);            // 5*4*2*4*64 frags (160 KB)
    bf16x8* wlbuf = whbuf + NL * 4 * 2 * 4 * 64;    // 160 KB

    const size_t zero_bytes = (size_t)(NN + NG * DD + NG + NL * 128) * sizeof(float);
    hipMemsetAsync(deg, 0, zero_bytes, stream);

    // ---- W fragment prep (all layers, one dispatch) ----
    wprep_kernel<<<(NL * 4 * 2 * 4 * 64 + 255) / 256, 256, 0, stream>>>(
        Wk, Wq, Wv, Ws, whbuf, wlbuf);

    // ---- CSR build ----
    deg_kernel<<<(NE + 255) / 256, 256, 0, stream>>>(ei, deg);
    scan_partial_kernel<<<NCHUNK, 256, 0, stream>>>(deg, psums);
    scan_offsets_kernel<<<1, 64, 0, stream>>>(psums, rowst);
    scan_final_kernel<<<NCHUNK, 256, 0, stream>>>(deg, psums, rowst, cursor);
    fill_kernel<<<(NE + 255) / 256, 256, 0, stream>>>(ei, cursor, csr);

    // ---- layers (BN folded into next GEMM / final) ----
    const float* hin = X;
    for (int l = 0; l < NL; l++) {
        float* hout = (l & 1) ? H1 : H0;
        const float* pS = l ? stats + (l - 1) * 128 : nullptr;
        const float* pG = l ? gamma + (l - 1) * 64  : nullptr;
        const float* pB = l ? beta  + (l - 1) * 64  : nullptr;
        gemm4_mfma<<<(NN + GROWS - 1) / GROWS, 256, 0, stream>>>(
            hin, whbuf + l * 2048, wlbuf + l * 2048,
            bk + l * 64, bq + l * 64, bv + l * 64, bconv + l * 64,
            pS, pG, pB, K, QVp, hout);
        gather_kernel<<<GATHER_BLOCKS, 256, 0, stream>>>(
            rowst, csr, K, QVp, hout, stats + l * 128);
        hin = hout;
    }

    pool_kernel<<<(NN + POOL_ROWS - 1) / POOL_ROWS, 64, 0, stream>>>(hin, batch, psum, pcnt);
    final_kernel<<<1, 256, 0, stream>>>(
        psum, pcnt, stats + 4 * 128, gamma + 4 * 64, beta + 4 * 64, Wlin, blin, out);
}

// Round 12
// 646.991 us; speedup vs baseline: 1.6732x; 1.1048x over previous
//
#include <hip/hip_runtime.h>

#define NN 50000
#define NE 800000
#define DD 64
#define NL 5
#define NG 256
#define NC 10
#define BN_EPS 1e-5f
#define NCHUNK ((NN + 255) / 256)   // 196
#define GROWS 128                    // rows per gemm block
#define GT (GROWS / 16)              // 16-row tiles per block
#define SAW 68                       // staged-A row stride (uints): 2-way conflicts only
#define GEMM_BLOCKS ((NN + GROWS - 1) / GROWS)   // 391

typedef __attribute__((ext_vector_type(8))) short bf16x8;
typedef __attribute__((ext_vector_type(4))) float f32x4;

__device__ inline float bf2f(unsigned short u) {
    return __uint_as_float((unsigned)u << 16);
}
__device__ inline unsigned short f2bf(float x) {   // RNE
    unsigned u = __float_as_uint(x);
    u += 0x7FFFu + ((u >> 16) & 1u);
    return (unsigned short)(u >> 16);
}

// Pack two floats as bf16 (RNE) into one uint: low16 = q, high16 = v.
__device__ inline unsigned int pack_bf16x2(float q, float v) {
    unsigned int uq = __float_as_uint(q);
    unsigned int uv = __float_as_uint(v);
    uq += 0x7FFFu + ((uq >> 16) & 1u);
    uv += 0x7FFFu + ((uv >> 16) & 1u);
    return (uv & 0xFFFF0000u) | (uq >> 16);
}

// Split fp32 into bf16 hi (RTZ) + bf16 lo (residual). hi+lo ~ x to ~2^-17.
__device__ inline void split_bf16(float x, short& h, short& l) {
    const unsigned u  = __float_as_uint(x);
    const unsigned hb = u & 0xFFFF0000u;
    h = (short)(hb >> 16);
    const float lo = x - __uint_as_float(hb);
    l = (short)(__float_as_uint(lo) >> 16);
}

// gate-fma for one packed bf16 q|v edge value (sigmoid via v_exp + v_rcp).
__device__ inline float gate_fma(float k, unsigned p, float acc) {
    const float q = __uint_as_float(p << 16);
    const float v = __uint_as_float(p & 0xFFFF0000u);
    const float e = __expf(-(k + q));
    return fmaf(__builtin_amdgcn_rcpf(1.f + e), v, acc);
}

// ---------------------------------------------------------------------------
// W-fragment prep (unchanged): split all layers' W into MFMA-read-order
// bf16 hi/lo fragment buffers.
// ---------------------------------------------------------------------------
__global__ __launch_bounds__(256) void wprep_kernel(
    const float* __restrict__ Wk, const float* __restrict__ Wq,
    const float* __restrict__ Wv, const float* __restrict__ Ws,
    bf16x8* __restrict__ whbuf, bf16x8* __restrict__ wlbuf)
{
    const int t = blockIdx.x * 256 + threadIdx.x;
    if (t >= NL * 4 * 2 * 4 * 64) return;
    const int lane = t & 63;
    const int w    = (t >> 6) & 3;
    const int c    = (t >> 8) & 1;
    const int m    = (t >> 9) & 3;
    const int l    = t >> 11;

    const float* Wm4[4] = {Wk, Wq, Wv, Ws};
    const float* W = Wm4[m] + l * 4096;
    const int col = w * 16 + (lane & 15);
    const int g   = lane >> 4;

    bf16x8 h, lo;
#pragma unroll
    for (int j = 0; j < 8; j++) {
        const int k = g * 8 + j + 32 * c;
        short hs, ls;
        split_bf16(W[k * DD + col], hs, ls);
        h[j] = hs; lo[j] = ls;
    }
    whbuf[t] = h;
    wlbuf[t] = lo;
}

// ---------------------------------------------------------------------------
// MFMA gemm4: K(bf16)/QVp(packed)/H(bf16) = BN(Hin) @ W* + b*. Split-bf16,
// 3 MFMAs per product, fp32 accumulate. Hin is fp32 (layer 0: X) or bf16
// (layers 1+: H) selected by hinF32 (wave-uniform branch).
// ---------------------------------------------------------------------------
__global__ __launch_bounds__(256) void gemm4_mfma(
    const void* __restrict__ HinV, const int hinF32,
    const bf16x8* __restrict__ whbuf, const bf16x8* __restrict__ wlbuf,
    const float* __restrict__ bk, const float* __restrict__ bq,
    const float* __restrict__ bv, const float* __restrict__ bs,
    const float* __restrict__ prevStats,   // null for layer 0
    const float* __restrict__ prevGamma, const float* __restrict__ prevBeta,
    unsigned short* __restrict__ Kb, unsigned int* __restrict__ QVp,
    unsigned short* __restrict__ OUTb)
{
    __shared__ unsigned int sA[GROWS * SAW];   // 34 KB packed split-bf16 A
    __shared__ float sAB[128];                 // a[64], b[64]
    const int tid = threadIdx.x;

    if (tid < 64) {
        float a = 1.f, b = 0.f;
        if (prevStats) {
            const float invN = 1.0f / (float)NN;
            const float mean = prevStats[tid] * invN;
            const float var  = prevStats[64 + tid] * invN - mean * mean;
            const float inv  = rsqrtf(var + BN_EPS);
            a = inv * prevGamma[tid];
            b = prevBeta[tid] - mean * a;
        }
        sAB[tid]      = a;
        sAB[64 + tid] = b;
    }
    __syncthreads();

    const int row0 = blockIdx.x * GROWS;
    for (int i = tid; i < GROWS * 16; i += 256) {
        const int row = i >> 4;
        const int k4  = (i & 15) * 4;
        float xs[4] = {0.f, 0.f, 0.f, 0.f};
        if (row0 + row < NN) {
            if (hinF32) {
                const float4 x = *(const float4*)((const float*)HinV + (size_t)(row0 + row) * DD + k4);
                xs[0] = x.x; xs[1] = x.y; xs[2] = x.z; xs[3] = x.w;
            } else {
                const ushort4 u = *(const ushort4*)((const unsigned short*)HinV + (size_t)(row0 + row) * DD + k4);
                xs[0] = bf2f(u.x); xs[1] = bf2f(u.y); xs[2] = bf2f(u.z); xs[3] = bf2f(u.w);
            }
        }
        unsigned int* dst = &sA[row * SAW + k4];
#pragma unroll
        for (int j = 0; j < 4; j++) {
            const float xv = fmaf(xs[j], sAB[k4 + j], sAB[64 + k4 + j]);
            short hs, ls;
            split_bf16(xv, hs, ls);
            dst[j] = ((unsigned int)(unsigned short)hs << 16) | (unsigned short)ls;
        }
    }

    const int wave = tid >> 6;    // column tile 0..3
    const int lane = tid & 63;
    const int n15  = lane & 15;
    const int g    = lane >> 4;   // quad
    const int col  = wave * 16 + n15;

    bf16x8 wh[4][2], wl[4][2];
    {
        const int base = wave * 64 + lane;
#pragma unroll
        for (int m = 0; m < 4; m++)
#pragma unroll
            for (int c = 0; c < 2; c++) {
                const int idx = m * 512 + c * 256 + base;
                wh[m][c] = whbuf[idx];
                wl[m][c] = wlbuf[idx];
            }
    }

    const float bkc = bk[col], bqc = bq[col], bvc = bv[col], bsc = bs[col];
    __syncthreads();

#pragma unroll 1
    for (int t = 0; t < GT; t++) {
        const int rowbase = row0 + t * 16;
        if (rowbase >= NN) break;   // NN % 16 == 0

        bf16x8 ah[2], al[2];
#pragma unroll
        for (int c = 0; c < 2; c++) {
            const uint4 u0 = *(const uint4*)&sA[(t * 16 + n15) * SAW + g * 8 + 32 * c];
            const uint4 u1 = *(const uint4*)&sA[(t * 16 + n15) * SAW + g * 8 + 32 * c + 4];
            const unsigned int us[8] = {u0.x, u0.y, u0.z, u0.w, u1.x, u1.y, u1.z, u1.w};
            bf16x8 h, l;
#pragma unroll
            for (int j = 0; j < 8; j++) {
                h[j] = (short)(us[j] >> 16);
                l[j] = (short)(us[j] & 0xFFFFu);
            }
            ah[c] = h; al[c] = l;
        }

        f32x4 acc[4];
#pragma unroll
        for (int m = 0; m < 4; m++) acc[m] = (f32x4){0.f, 0.f, 0.f, 0.f};

#pragma unroll
        for (int c = 0; c < 2; c++) {
#pragma unroll
            for (int m = 0; m < 4; m++) {
                acc[m] = __builtin_amdgcn_mfma_f32_16x16x32_bf16(ah[c], wh[m][c], acc[m], 0, 0, 0);
                acc[m] = __builtin_amdgcn_mfma_f32_16x16x32_bf16(al[c], wh[m][c], acc[m], 0, 0, 0);
                acc[m] = __builtin_amdgcn_mfma_f32_16x16x32_bf16(ah[c], wl[m][c], acc[m], 0, 0, 0);
            }
        }

#pragma unroll
        for (int r = 0; r < 4; r++) {
            const int row = rowbase + g * 4 + r;
            const size_t o = (size_t)row * DD + col;
            Kb[o]   = f2bf(acc[0][r] + bkc);
            QVp[o]  = pack_bf16x2(acc[1][r] + bqc, acc[2][r] + bvc);
            OUTb[o] = f2bf(acc[3][r] + bsc);
        }
    }
}

// ---------------------------------------------------------------------------
// CSR build: histogram of dst, two-level exclusive scan, scatter fill.
// ---------------------------------------------------------------------------
__global__ __launch_bounds__(256) void deg_kernel(
    const int* __restrict__ ei, int* __restrict__ deg)
{
    const int e = blockIdx.x * 256 + threadIdx.x;
    if (e < NE) atomicAdd(&deg[ei[NE + e]], 1);
}

__global__ __launch_bounds__(256) void scan_partial_kernel(
    const int* __restrict__ deg, int* __restrict__ psums)
{
    __shared__ int ls[256];
    const int i = blockIdx.x * 256 + threadIdx.x;
    ls[threadIdx.x] = (i < NN) ? deg[i] : 0;
    __syncthreads();
    for (int off = 128; off > 0; off >>= 1) {
        if (threadIdx.x < off) ls[threadIdx.x] += ls[threadIdx.x + off];
        __syncthreads();
    }
    if (threadIdx.x == 0) psums[blockIdx.x] = ls[0];
}

__global__ void scan_offsets_kernel(int* __restrict__ psums, int* __restrict__ rowst)
{
    if (threadIdx.x == 0) {
        int running = 0;
        for (int i = 0; i < NCHUNK; i++) {
            int t = psums[i];
            psums[i] = running;
            running += t;
        }
        rowst[NN] = running;  // == NE
    }
}

__global__ __launch_bounds__(256) void scan_final_kernel(
    const int* __restrict__ deg, const int* __restrict__ psums,
    int* __restrict__ rowst, int* __restrict__ cursor)
{
    __shared__ int ls[256];
    const int i = blockIdx.x * 256 + threadIdx.x;
    const int x = (i < NN) ? deg[i] : 0;
    ls[threadIdx.x] = x;
    __syncthreads();
    for (int off = 1; off < 256; off <<= 1) {
        int v = (threadIdx.x >= off) ? ls[threadIdx.x - off] : 0;
        __syncthreads();
        ls[threadIdx.x] += v;
        __syncthreads();
    }
    if (i < NN) {
        const int excl = psums[blockIdx.x] + ls[threadIdx.x] - x;
        rowst[i]  = excl;
        cursor[i] = excl;
    }
}

__global__ __launch_bounds__(256) void fill_kernel(
    const int* __restrict__ ei, int* __restrict__ cursor, int* __restrict__ csr)
{
    const int e = blockIdx.x * 256 + threadIdx.x;
    if (e < NE) {
        const int src = ei[e];
        const int dst = ei[NE + e];
        csr[atomicAdd(&cursor[dst], 1)] = src;
    }
}

// ---------------------------------------------------------------------------
// Gather, XCD-aligned: block j covers a 32-row sub-window of gemm block
// g = (j%8) + 8*((j/8)/4), so g%8 == j%8 -> under round-robin block->XCD
// dispatch, the K/H rows this block reads were written into the SAME XCD's
// L2 by gemm (and H written here is L2-warm for the next gemm). Inner loop
// is the proven R10 unroll-4 (4 loads in flight). K/H in bf16.
// Stats computed on the bf16-ROUNDED h (consistent with downstream reads).
// ---------------------------------------------------------------------------
#define GATHER_BLOCKS (8 * 49 * 4)   // 1568
__global__ __launch_bounds__(256) void gather_kernel(
    const int* __restrict__ rowst, const int* __restrict__ csr,
    const unsigned short* __restrict__ Kb, const unsigned int* __restrict__ QVp,
    unsigned short* Hb, float* __restrict__ stats)
{
    const int tid = threadIdx.x;
    const int c   = tid & 63;
    const int wv  = tid >> 6;

    const int j     = blockIdx.x;
    const int lane8 = j & 7;
    const int idx   = j >> 3;               // 0..195
    const int g     = lane8 + 8 * (idx >> 2);
    const int sub   = idx & 3;
    const int base  = g * GROWS + sub * 32;

    float s = 0.f, s2 = 0.f;

    for (int t = 0; t < 8; t++) {
        const int n = base + wv + t * 4;
        if (n >= NN) break;
        const unsigned rowoff = (unsigned)(n * DD + c);
        const float k     = bf2f(Kb[rowoff]);
        const float hskip = bf2f(Hb[rowoff]);
        const int e0 = rowst[n], e1 = rowst[n + 1];
        float acc = 0.f;
        int i = e0;
        for (; i + 4 <= e1; i += 4) {
            const int s0 = csr[i], s1 = csr[i + 1], s2i = csr[i + 2], s3 = csr[i + 3];
            const unsigned p0 = QVp[(unsigned)(s0  * DD + c)];
            const unsigned p1 = QVp[(unsigned)(s1  * DD + c)];
            const unsigned p2 = QVp[(unsigned)(s2i * DD + c)];
            const unsigned p3 = QVp[(unsigned)(s3  * DD + c)];
            acc = gate_fma(k, p0, acc);
            acc = gate_fma(k, p1, acc);
            acc = gate_fma(k, p2, acc);
            acc = gate_fma(k, p3, acc);
        }
        for (; i < e1; i++) {
            const unsigned p0 = QVp[(unsigned)(csr[i] * DD + c)];
            acc = gate_fma(k, p0, acc);
        }
        const float o = fmaxf(hskip + acc, 0.f);
        const unsigned short ob = f2bf(o);
        Hb[rowoff] = ob;
        const float orr = bf2f(ob);
        s += orr;
        s2 += orr * orr;
    }

    __shared__ float ls[256], ls2[256];
    ls[tid]  = s;
    ls2[tid] = s2;
    __syncthreads();
    if (tid < 64) {
        const float a = ls[tid]  + ls[tid + 64]  + ls[tid + 128]  + ls[tid + 192];
        const float b = ls2[tid] + ls2[tid + 64] + ls2[tid + 128] + ls2[tid + 192];
        atomicAdd(&stats[c], a);
        atomicAdd(&stats[64 + c], b);
    }
}

// ---------------------------------------------------------------------------
// Pooled segment-sum over bf16 H (batch sorted -> run-length accumulate).
// 782 blocks x 64 threads, 64 rows each.
// ---------------------------------------------------------------------------
#define POOL_ROWS 64
__global__ __launch_bounds__(64) void pool_kernel(
    const unsigned short* __restrict__ Hb, const int* __restrict__ batch,
    float* __restrict__ psum, float* __restrict__ pcnt)
{
    const int c  = threadIdx.x;
    const int r0 = blockIdx.x * POOL_ROWS;
    if (r0 >= NN) return;
    const int r1 = min(r0 + POOL_ROWS, NN);

    int cur = batch[r0];
    float acc = 0.f, cnt = 0.f;
    for (int r = r0; r < r1; r++) {
        const int g = batch[r];
        if (g != cur) {
            atomicAdd(&psum[cur * DD + c], acc);
            if (c == 0) atomicAdd(&pcnt[cur], cnt);
            acc = 0.f; cnt = 0.f; cur = g;
        }
        acc += bf2f(Hb[(size_t)r * DD + c]);
        cnt += 1.f;
    }
    atomicAdd(&psum[cur * DD + c], acc);
    if (c == 0) atomicAdd(&pcnt[cur], cnt);
}

// ---------------------------------------------------------------------------
// Final: pooled mean -> folded last-layer BN affine -> logits -> softmax.
// ---------------------------------------------------------------------------
__global__ __launch_bounds__(256) void final_kernel(
    const float* __restrict__ psum, const float* __restrict__ pcnt,
    const float* __restrict__ stats,
    const float* __restrict__ gamma, const float* __restrict__ beta,
    const float* __restrict__ Wlin, const float* __restrict__ blin,
    float* __restrict__ out)
{
    const int g = blockIdx.x * blockDim.x + threadIdx.x;
    if (g >= NG) return;

    const float invc = 1.0f / fmaxf(pcnt[g], 1.0f);
    const float invN = 1.0f / (float)NN;
    float p[DD];
#pragma unroll
    for (int d = 0; d < DD; d++) {
        const float mean = stats[d] * invN;
        const float var  = stats[64 + d] * invN - mean * mean;
        const float inv  = rsqrtf(var + BN_EPS);
        const float a = inv * gamma[d];
        const float b = beta[d] - mean * a;
        p[d] = fmaf(psum[g * DD + d] * invc, a, b);
    }

    float logits[NC];
    float m = -1e30f;
#pragma unroll
    for (int c = 0; c < NC; c++) {
        float acc = blin[c];
#pragma unroll
        for (int d = 0; d < DD; d++) acc = fmaf(p[d], Wlin[d * NC + c], acc);
        logits[c] = acc;
        m = fmaxf(m, acc);
    }
    float sum = 0.f;
#pragma unroll
    for (int c = 0; c < NC; c++) {
        logits[c] = __expf(logits[c] - m);
        sum += logits[c];
    }
    const float inv = 1.f / sum;
#pragma unroll
    for (int c = 0; c < NC; c++) out[g * NC + c] = logits[c] * inv;
}

// ---------------------------------------------------------------------------
extern "C" void kernel_launch(void* const* d_in, const int* in_sizes, int n_in,
                              void* d_out, int out_size, void* d_ws, size_t ws_size,
                              hipStream_t stream)
{
    const float* X     = (const float*)d_in[0];
    const int*   ei    = (const int*)d_in[1];
    const int*   batch = (const int*)d_in[2];
    const float* Wk    = (const float*)d_in[3];
    const float* Wq    = (const float*)d_in[4];
    const float* Wv    = (const float*)d_in[5];
    const float* Ws    = (const float*)d_in[6];
    const float* bk    = (const float*)d_in[7];
    const float* bq    = (const float*)d_in[8];
    const float* bv    = (const float*)d_in[9];
    const float* bconv = (const float*)d_in[10];
    const float* gamma = (const float*)d_in[11];
    const float* beta  = (const float*)d_in[12];
    const float* Wlin  = (const float*)d_in[13];
    const float* blin  = (const float*)d_in[14];
    float* out = (float*)d_out;

    const size_t M = (size_t)NN * DD;
    unsigned short* Kb  = (unsigned short*)d_ws;      // M bf16
    unsigned int*   QVp = (unsigned int*)(Kb + M);    // M packed bf16 q|v
    unsigned short* H0  = (unsigned short*)(QVp + M); // M bf16
    unsigned short* H1  = H0 + M;                     // M bf16
    // --- contiguous zero-init region ---
    int*   deg   = (int*)(H1 + M);                    // NN
    float* psum  = (float*)(deg + NN);                // NG*DD
    float* pcnt  = psum + (size_t)NG * DD;            // NG
    float* stats = pcnt + NG;                         // NL*128
    // --- end zero region ---
    int* rowst  = (int*)(stats + NL * 128);           // NN+1
    int* cursor = rowst + NN + 1;                     // NN
    int* psums  = cursor + NN;                        // 256
    int* csr    = psums + 256;                        // NE
    bf16x8* whbuf = (bf16x8*)(csr + NE);              // NL*2048 frags
    bf16x8* wlbuf = whbuf + NL * 2048;

    const size_t zero_bytes = (size_t)(NN + NG * DD + NG + NL * 128) * sizeof(float);
    hipMemsetAsync(deg, 0, zero_bytes, stream);

    // ---- W fragment prep ----
    wprep_kernel<<<(NL * 2048 + 255) / 256, 256, 0, stream>>>(
        Wk, Wq, Wv, Ws, whbuf, wlbuf);

    // ---- CSR build ----
    deg_kernel<<<(NE + 255) / 256, 256, 0, stream>>>(ei, deg);
    scan_partial_kernel<<<NCHUNK, 256, 0, stream>>>(deg, psums);
    scan_offsets_kernel<<<1, 64, 0, stream>>>(psums, rowst);
    scan_final_kernel<<<NCHUNK, 256, 0, stream>>>(deg, psums, rowst, cursor);
    fill_kernel<<<(NE + 255) / 256, 256, 0, stream>>>(ei, cursor, csr);

    // ---- layers (BN folded into next GEMM / final) ----
    const void* hin = (const void*)X;
    int hinF32 = 1;
    for (int l = 0; l < NL; l++) {
        unsigned short* hout = (l & 1) ? H1 : H0;
        const float* pS = l ? stats + (l - 1) * 128 : nullptr;
        const float* pG = l ? gamma + (l - 1) * 64  : nullptr;
        const float* pB = l ? beta  + (l - 1) * 64  : nullptr;
        gemm4_mfma<<<GEMM_BLOCKS, 256, 0, stream>>>(
            hin, hinF32, whbuf + l * 2048, wlbuf + l * 2048,
            bk + l * 64, bq + l * 64, bv + l * 64, bconv + l * 64,
            pS, pG, pB, Kb, QVp, hout);
        gather_kernel<<<GATHER_BLOCKS, 256, 0, stream>>>(
            rowst, csr, Kb, QVp, hout, stats + l * 128);
        hin = (const void*)hout;
        hinF32 = 0;
    }

    pool_kernel<<<(NN + POOL_ROWS - 1) / POOL_ROWS, 64, 0, stream>>>(
        (const unsigned short*)hin, batch, psum, pcnt);
    final_kernel<<<1, 256, 0, stream>>>(
        psum, pcnt, stats + 4 * 128, gamma + 4 * 64, beta + 4 * 64, Wlin, blin, out);
}